// Round 5
// baseline (6848.417 us; speedup 1.0000x reference)
//
#include <hip/hip_runtime.h>
#include <math.h>

#define NTHR 1024   // threads per block (2 threads per point)
#define DD   128    // feature dim
#define HD   64     // dims per thread (16 x float4, NAMED scalars -> no alloca)

typedef unsigned long long ull;

#define FOR16(M) M(0) M(1) M(2) M(3) M(4) M(5) M(6) M(7) \
                 M(8) M(9) M(10) M(11) M(12) M(13) M(14) M(15)

// packed argmax key: (ordered f32)<<32 | ~idx  -> max() gives argmax with
// smallest-index tie-break, matching jnp.argmax first-occurrence.
__device__ __forceinline__ ull pkkey(float f, unsigned idx) {
  unsigned u = __float_as_uint(f);
  u = (u & 0x80000000u) ? ~u : (u | 0x80000000u);
  return ((ull)u << 32) | (ull)(~idx);
}

__device__ __forceinline__ ull wredmax(ull v) {
#pragma unroll
  for (int m = 32; m; m >>= 1) {
    ull o = __shfl_xor(v, m, 64);
    v = (o > v) ? o : v;
  }
  return v;
}

// Fused {block argmax -> tagged slot store -> all-blocks poll -> local reduce}.
// Slot: f32bits<<32 | (t+1)<<17 | idx. Double-buffered by t&1 (blocks at most
// one phase apart). memset-0 init never matches a tag >= 1.
__device__ __forceinline__ int roundSync(float val, unsigned pidx, int t,
                                         ull* __restrict__ partials, int nblk,
                                         ull* s_w, ull* s_r,
                                         int tid, int lane, int wid, int blockId) {
  ull key = wredmax(pkkey(val, pidx));
  if (lane == 0) s_w[wid] = key;
  __syncthreads();
  if (tid == 0) {
    ull m = s_w[0];
#pragma unroll
    for (int i = 1; i < NTHR / 64; ++i) { ull o = s_w[i]; if (o > m) m = o; }
    unsigned idx = ~(unsigned)m;
    ull slotv = (m & 0xFFFFFFFF00000000ull) | ((ull)(unsigned)(t + 1) << 17) | (ull)idx;
    __hip_atomic_store(&partials[(t & 1) * nblk + blockId], slotv,
                       __ATOMIC_RELEASE, __HIP_MEMORY_SCOPE_AGENT);
  }
  // poll all slots in parallel (one per thread), short-sleep backoff
  ull ck = 0;
  if (tid < nblk) {
    ull* slot = &partials[(t & 1) * nblk + tid];
    const unsigned tag = (unsigned)(t + 1);
    ull v = __hip_atomic_load(slot, __ATOMIC_ACQUIRE, __HIP_MEMORY_SCOPE_AGENT);
    while (((unsigned)(v >> 17) & 0x7FFFu) != tag) {
      __builtin_amdgcn_s_sleep(2);
      v = __hip_atomic_load(slot, __ATOMIC_ACQUIRE, __HIP_MEMORY_SCOPE_AGENT);
    }
    unsigned idx = (unsigned)v & 0x1FFFFu;
    ck = (v & 0xFFFFFFFF00000000ull) | (ull)(~idx);
  }
  ck = wredmax(ck);
  if (lane == 0) s_r[wid] = ck;
  __syncthreads();
  ull m = s_r[0];
#pragma unroll
  for (int i = 1; i < NTHR / 64; ++i) { ull o = s_r[i]; if (o > m) m = o; }
  return (int)(~(unsigned)m);
}

// stage normalized selected row into LDS (f32 squares, exact f64 sum, f32 sqrt, IEEE f32 div)
__device__ __forceinline__ void stage(const float* __restrict__ feat, int c,
                                      float* s_sel, float* s_nrm, int tid, int lane) {
  const float* __restrict__ row = feat + (size_t)c * DD;
  if (tid < 64) {
    float x1 = row[lane], x2 = row[lane + 64];
    double s = (double)(x1 * x1) + (double)(x2 * x2);
#pragma unroll
    for (int m = 32; m; m >>= 1) s += __shfl_xor(s, m, 64);
    if (lane == 0) *s_nrm = fmaxf(sqrtf((float)s), 1e-12f);
  }
  __syncthreads();
  const float nm = *s_nrm;
  if (tid < DD) s_sel[tid] = row[tid] / nm;
  __syncthreads();
}

// distance accumulate over one named float4 (f32 diffs/squares, exact f64 sum)
#define DACC(i) { float4 c = sp[i]; \
  float dx = q##i.x - c.x, dy = q##i.y - c.y, dz = q##i.z - c.z, dw = q##i.w - c.w; \
  b0 += (double)(dx * dx); b1 += (double)(dy * dy); \
  b2 += (double)(dz * dz); b3 += (double)(dw * dw); }

#define DIST_TO(dvar) do { \
  const float4* sp = reinterpret_cast<const float4*>(s_sel) + (half << 4); \
  double b0 = 0.0, b1 = 0.0, b2 = 0.0, b3 = 0.0; \
  FOR16(DACC) \
  double ss = (b0 + b1) + (b2 + b3); \
  ss += __shfl_xor(ss, 1, 64); /* combine pair halves, exact to ~2^-52 */ \
  dvar = sqrtf((float)ss); \
} while (0)

// waves_per_eu(4,4): 16-wave blocks at 1 block/CU = exactly 4 waves/EU; max=4
// lifts the allocator's occupancy target -> 128-VGPR/wave budget, enough for
// the 64 resident point floats + working set.
__global__ __launch_bounds__(NTHR)
__attribute__((amdgpu_waves_per_eu(4, 4)))
void fps_kernel(const float* __restrict__ feat, const float* __restrict__ att,
                const int* __restrict__ kptr, int* __restrict__ out,
                ull* __restrict__ partials, int N, int nblk) {
  __shared__ ull s_w[NTHR / 64];
  __shared__ ull s_r[NTHR / 64];
  __shared__ alignas(16) float s_sel[DD];
  __shared__ float s_nrm;

  const int tid  = threadIdx.x;
  const int lane = tid & 63;
  const int wid  = tid >> 6;
  const int gid  = blockIdx.x * NTHR + tid;
  const int pidx = gid >> 1;   // point index (2 threads per point)
  const int half = tid & 1;    // which 64-dim half this thread owns
  const int k    = kptr[0];

  if (k >= N) {  // reference returns arange(N)
    for (int i = gid; i < N; i += nblk * NTHR) out[i] = i;
    return;
  }

  // ---- load my 64-dim half into 16 NAMED float4 registers (no array!)
  const float4* __restrict__ qbase = reinterpret_cast<const float4*>(feat + (size_t)gid * HD);
  float4 q0, q1, q2, q3, q4, q5, q6, q7, q8, q9, q10, q11, q12, q13, q14, q15;
#define LOADQ(i) q##i = qbase[i];
  FOR16(LOADQ)
#undef LOADQ

  // ---- L2-normalize (f32 squares, exact f64 sum across both halves)
  {
    double a0 = 0.0, a1 = 0.0, a2 = 0.0, a3 = 0.0;
#define NACC(i) a0 += (double)(q##i.x * q##i.x); a1 += (double)(q##i.y * q##i.y); \
                a2 += (double)(q##i.z * q##i.z); a3 += (double)(q##i.w * q##i.w);
    FOR16(NACC)
#undef NACC
    double s = (a0 + a1) + (a2 + a3);
    s += __shfl_xor(s, 1, 64);
    float nm = fmaxf(sqrtf((float)s), 1e-12f);
    // IEEE f32 divide (matches reference elementwise rounding), then pin each
    // component in a VGPR: asm output values cannot be rematerialized.
#define DIVPIN(i) q##i.x /= nm; q##i.y /= nm; q##i.z /= nm; q##i.w /= nm; \
    asm volatile("" : "+v"(q##i.x), "+v"(q##i.y), "+v"(q##i.z), "+v"(q##i.w));
    FOR16(DIVPIN)
#undef DIVPIN
  }

  // ---- phase A: argmax(attention_scores)
  int far = roundSync(att[pidx], (unsigned)pidx, 0, partials, nblk,
                      s_w, s_r, tid, lane, wid, blockIdx.x);
  if (gid == 0) out[0] = far;

  stage(feat, far, s_sel, &s_nrm, tid, lane);
  float mind;
  DIST_TO(mind);
  if (pidx == far) mind = -__builtin_inff();

  // ---- main FPS loop
  for (int t = 1; t < k; ++t) {
    far = roundSync(mind, (unsigned)pidx, t, partials, nblk,
                    s_w, s_r, tid, lane, wid, blockIdx.x);
    if (gid == 0) out[t] = far;

    stage(feat, far, s_sel, &s_nrm, tid, lane);
    float d;
    DIST_TO(d);
    mind = fminf(mind, d);
    if (pidx == far) mind = -__builtin_inff();
  }
}

extern "C" void kernel_launch(void* const* d_in, const int* in_sizes, int n_in,
                              void* d_out, int out_size, void* d_ws, size_t ws_size,
                              hipStream_t stream) {
  const float* feat = (const float*)d_in[0];
  const float* att  = (const float*)d_in[1];
  const int*   kptr = (const int*)d_in[2];
  int* out = (int*)d_out;

  const int N    = in_sizes[1];        // 131072
  const int nblk = (2 * N) / NTHR;     // 256 blocks -> 1 per CU, all co-resident

  ull* partials = (ull*)d_ws;
  // zero the tagged slots every call (graph-replay determinism; tag>=1 never matches 0)
  hipMemsetAsync(d_ws, 0, (size_t)(2 * nblk * sizeof(ull)), stream);
  fps_kernel<<<nblk, NTHR, 0, stream>>>(feat, att, kptr, out, partials, N, nblk);
}